// Round 7
// baseline (96.336 us; speedup 1.0000x reference)
//
#include <hip/hip_runtime.h>
#include <hip/hip_bf16.h>

#define BB 4
#define NN 4096
#define DD 64
#define CC 8                 // column chunks (grid.z)
#define CHUNK (NN / CC)      // 512 cols per block
#define HPB 1024             // hit capacity per block (expect <~100)
#define PREP_BLOCKS 512      // BN/32
#define FIN_BLOCKS 64        // BN/256
#define PSCALE 240.2244818f  // 200 * sqrt(log2(e)) : |p'i-p'j|^2 = PD*log2(e)
#define K2L 2.885390082f     // 2*log2(e)  (folded into f1 bf16)
#define NL2E -1.442695041f   // -log2(e)
#define LN2 0.6931471805599453f

typedef __attribute__((ext_vector_type(8))) short bf16x8;
typedef __attribute__((ext_vector_type(4))) float f32x4;

// workspace layout (bytes)
static constexpr size_t BN = (size_t)BB * NN;
static constexpr size_t OFF_F1B = 0;                          // bf16 [BN][D] (pre-scaled by K2L)
static constexpr size_t OFF_F2B = OFF_F1B + BN * DD * 2;      // bf16 [BN][D]
static constexpr size_t OFF_PP4 = OFF_F2B + BN * DD * 2;      // float4 [BN] {p'x,p'y,p'z,|p'|^2}
static constexpr size_t OFF_NB2 = OFF_PP4 + BN * 16;          // f32 [BN]  -|f2|^2*log2e
static constexpr size_t OFF_PZF = OFF_NB2 + BN * 4;           // f32 [CC][BN] partial Zf
static constexpr size_t OFF_ZP  = OFF_PZF + (size_t)CC * BN * 4;  // f32 [BN] (zeroed by prep)
static constexpr size_t OFF_SP  = OFF_ZP + BN * 4;            // f32 [BN] (zeroed by prep)
static constexpr size_t OFF_PRG = OFF_SP + BN * 4;            // f32 [PREP_BLOCKS] reg partials
static constexpr size_t OFF_CEP = OFF_PRG + PREP_BLOCKS * 4;  // f32 [FIN_BLOCKS] ce partials

__device__ __forceinline__ unsigned short f2bf(float x) {
  unsigned int u = __float_as_uint(x);
  u += 0x7FFFu + ((u >> 16) & 1u);   // round-to-nearest-even
  return (unsigned short)(u >> 16);
}
__device__ __forceinline__ float bf2f(short s) {
  return __uint_as_float(((unsigned)(unsigned short)s) << 16);
}

// ---- prep: bf16 convert (f1 scaled) + norms + points + reg partial + Zp/Sp zero ----
__global__ __launch_bounds__(256) void prep_kernel(
    const float* __restrict__ pts, const float* __restrict__ f1,
    const float* __restrict__ f2, unsigned short* __restrict__ f1b,
    unsigned short* __restrict__ f2b, float4* __restrict__ pp4,
    float* __restrict__ nb2, float* __restrict__ pregs,
    float* __restrict__ Zp, float* __restrict__ Sp) {
  const int R0 = blockIdx.x * 32;
  const int t = threadIdx.x;
  const float4* f1v = (const float4*)(f1 + (size_t)R0 * DD);
  const float4* f2v = (const float4*)(f2 + (size_t)R0 * DD);
  ushort4* o1 = (ushort4*)(f1b + (size_t)R0 * DD);
  ushort4* o2 = (ushort4*)(f2b + (size_t)R0 * DD);
  if (t < 32) { Zp[R0 + t] = 0.f; Sp[R0 + t] = 0.f; }
  float regsum = 0.f;
#pragma unroll
  for (int p = 0; p < 2; ++p) {
    int c = t + p * 256;                 // float4-chunk in [0,512); row = R0 + c/16
    float4 a = f1v[c], bv = f2v[c];
    ushort4 ua, ub;
    ua.x = f2bf(a.x * K2L); ua.y = f2bf(a.y * K2L);
    ua.z = f2bf(a.z * K2L); ua.w = f2bf(a.w * K2L);
    ub.x = f2bf(bv.x); ub.y = f2bf(bv.y); ub.z = f2bf(bv.z); ub.w = f2bf(bv.w);
    o1[c] = ua; o2[c] = ub;
    float s1 = a.x * a.x + a.y * a.y + a.z * a.z + a.w * a.w;
    float s2 = bv.x * bv.x + bv.y * bv.y + bv.z * bv.z + bv.w * bv.w;
    regsum += s1 + s2;
    float s2r = s2;
#pragma unroll
    for (int m = 1; m <= 8; m <<= 1) s2r += __shfl_xor(s2r, m, 64);
    if ((t & 15) == 0) nb2[R0 + (c >> 4)] = NL2E * s2r;
  }
  if (t < 32) {
    int row = R0 + t;
    float px = pts[row * 3 + 0] * PSCALE;
    float py = pts[row * 3 + 1] * PSCALE;
    float pz = pts[row * 3 + 2] * PSCALE;
    pp4[row] = make_float4(px, py, pz, fmaf(px, px, fmaf(py, py, pz * pz)));
  }
  __shared__ float red[256];
  red[t] = regsum;
  __syncthreads();
  for (int k = 128; k > 0; k >>= 1) {
    if (t < k) red[t] += red[t + k];
    __syncthreads();
  }
  if (t == 0) pregs[blockIdx.x] = red[0];
}

// ---- stream: Zf via direct-global MFMA fragments (no LDS staging, no tile barriers)
//      + point hit-scan with in-block resolve.
// grid (NN/64, BB, CC), block 256. Wave owns 16 rows x 512 cols; block 64 rows.
__global__ __launch_bounds__(256, 4) void stream_kernel(
    const unsigned short* __restrict__ f1b, const unsigned short* __restrict__ f2b,
    const float4* __restrict__ pp4, const float* __restrict__ nb2g,
    float* __restrict__ pZf, float* __restrict__ Zp, float* __restrict__ Sp) {
  __shared__ uint2 hbuf[HPB];                  // 8KB hit buffer
  __shared__ unsigned hcnt;

  const int b = blockIdx.y;
  const int ck = blockIdx.z;
  const int rowbase = blockIdx.x * 64;
  const int tid = threadIdx.x;
  const int wave = tid >> 6;
  const int lane = tid & 63;
  const int l15 = lane & 15;
  const int l4 = lane >> 4;
  if (tid == 0) hcnt = 0;

  // A fragments: f1 rows for this wave (constant across j loop)
  const unsigned short* f1row = f1b + (size_t)(b * NN + rowbase + wave * 16 + l15) * DD;
  bf16x8 af0 = *(const bf16x8*)(f1row + l4 * 8);
  bf16x8 af1 = *(const bf16x8*)(f1row + 32 + l4 * 8);

  // point-scan row constants: 4 rows per thread (rows fixed for whole block)
  float m2x[4], m2y[4], m2z[4], xw[4];
#pragma unroll
  for (int k = 0; k < 4; ++k) {
    float4 p = pp4[b * NN + rowbase + (tid & 15) * 4 + k];
    m2x[k] = -2.f * p.x; m2y[k] = -2.f * p.y; m2z[k] = -2.f * p.z; xw[k] = p.w;
  }
  __syncthreads();   // hcnt visible

  const int colbase = ck * CHUNK;
  const unsigned short* f2base = f2b + (size_t)(b * NN + colbase) * DD;
  const float* nbcol = nb2g + b * NN + colbase;

  float Zf[4] = {0.f, 0.f, 0.f, 0.f};
#pragma unroll 4
  for (int s = 0; s < CHUNK / 16; ++s) {       // 32 iters of 16 cols
    const unsigned short* f2r = f2base + (size_t)(s * 16 + l15) * DD;
    bf16x8 bf0 = *(const bf16x8*)(f2r + l4 * 8);        // direct L2->VGPR
    bf16x8 bf1 = *(const bf16x8*)(f2r + 32 + l4 * 8);
    float nb = nbcol[s * 16 + l15];
    f32x4 acc = {nb, nb, nb, nb};
    acc = __builtin_amdgcn_mfma_f32_16x16x32_bf16(af0, bf0, acc, 0, 0, 0);
    acc = __builtin_amdgcn_mfma_f32_16x16x32_bf16(af1, bf1, acc, 0, 0, 0);
#pragma unroll
    for (int r = 0; r < 4; ++r) Zf[r] += __builtin_amdgcn_exp2f(acc[r]);
  }

  // point scan: thread covers 4 rows x 32 cols of the 64x512 block tile
  const float4* pcol = pp4 + b * NN + colbase;
  const int cg = tid >> 4;
#pragma unroll 4
  for (int cc = 0; cc < 32; ++cc) {
    int c = cg * 32 + cc;                       // CHUNK-local col
    float4 pj = pcol[c];
    float ww = pj.w;
    float pd[4];
#pragma unroll
    for (int k = 0; k < 4; ++k)
      pd[k] = fmaf(m2x[k], pj.x, fmaf(m2y[k], pj.y, fmaf(m2z[k], pj.z, xw[k] + ww)));
    float mn = fminf(fminf(pd[0], pd[1]), fminf(pd[2], pd[3]));
    if (mn < 126.f) {
#pragma unroll
      for (int k = 0; k < 4; ++k)
        if (pd[k] < 126.f) {
          unsigned slot = atomicAdd(&hcnt, 1u);
          if (slot < HPB)
            hbuf[slot] = make_uint2((((unsigned)((tid & 15) * 4 + k)) << 9) | (unsigned)c,
                                    __float_as_uint(pd[k]));
        }
    }
  }

  // merge Zf across the 16 lanes sharing rows; write partials
#pragma unroll
  for (int m = 1; m <= 8; m <<= 1)
#pragma unroll
    for (int r = 0; r < 4; ++r) Zf[r] += __shfl_xor(Zf[r], m, 64);
  if (l15 == 0) {
    size_t base = (size_t)ck * BN + b * NN + rowbase + wave * 16 + l4 * 4;
#pragma unroll
    for (int r = 0; r < 4; ++r) pZf[base + r] = Zf[r];
  }

  // resolve hits: recompute bf16 dot, accumulate global Zp/Sp
  __syncthreads();
  unsigned n = hcnt; if (n > HPB) n = HPB;
  for (unsigned idx = tid; idx < n; idx += 256) {
    uint2 h = hbuf[idx];
    unsigned rowg = b * NN + rowbase + (h.x >> 9);
    unsigned jg = b * NN + colbase + (h.x & 511u);
    const bf16x8* A = (const bf16x8*)(f1b + (size_t)rowg * DD);
    const bf16x8* Bv = (const bf16x8*)(f2b + (size_t)jg * DD);
    float dot = 0.f;                       // = K2L * dot(f1,f2)  (f1 pre-scaled)
#pragma unroll
    for (int c = 0; c < 8; ++c) {
      bf16x8 av = A[c], bv = Bv[c];
#pragma unroll
      for (int e = 0; e < 8; ++e) dot = fmaf(bf2f(av[e]), bf2f(bv[e]), dot);
    }
    float t2 = dot + nb2g[jg];             // (2dot - b2)*log2e
    float g = __builtin_amdgcn_exp2f(-__uint_as_float(h.y));
    atomicAdd(&Zp[rowg], g);
    atomicAdd(&Sp[rowg], g * t2);
  }
}

// ---------------- finalize: ce per row, partial per block ---------------------
__global__ __launch_bounds__(256) void finalize_kernel(
    const float* __restrict__ pZf, const float* __restrict__ Zp,
    const float* __restrict__ Sp, const float* __restrict__ wts,
    float* __restrict__ ceparts) {
  const int i = blockIdx.x * 256 + threadIdx.x;    // row in [0, BN)
  float zf = 0.f;
#pragma unroll
  for (int c = 0; c < CC; ++c) zf += pZf[(size_t)c * BN + i];
  float ce = wts[i] * (LN2 * (__builtin_amdgcn_logf(zf) - Sp[i] / Zp[i]));
  __shared__ float red[256];
  red[threadIdx.x] = ce;
  __syncthreads();
  for (int k = 128; k > 0; k >>= 1) {
    if (threadIdx.x < k) red[threadIdx.x] += red[threadIdx.x + k];
    __syncthreads();
  }
  if (threadIdx.x == 0) ceparts[blockIdx.x] = red[0];
}

// ---------------- out: reduce partials into d_out (plain stores) --------------
__global__ __launch_bounds__(256) void out_kernel(
    const float* __restrict__ ceparts, const float* __restrict__ pregs,
    float* __restrict__ out) {
  const int w = threadIdx.x >> 6, lane = threadIdx.x & 63;
  float ps = pregs[w * 128 + lane] + pregs[w * 128 + 64 + lane];
#pragma unroll
  for (int m = 1; m <= 32; m <<= 1) ps += __shfl_xor(ps, m, 64);
  float cs = (lane < 16) ? ceparts[w * 16 + lane] : 0.f;
#pragma unroll
  for (int m = 1; m <= 8; m <<= 1) cs += __shfl_xor(cs, m, 64);
  if (lane == 0) {
    out[w] = cs;
    out[BB + w] = ps * (1.f / ((float)NN * DD));
  }
}

extern "C" void kernel_launch(void* const* d_in, const int* in_sizes, int n_in,
                              void* d_out, int out_size, void* d_ws, size_t ws_size,
                              hipStream_t stream) {
  const float* pts = (const float*)d_in[0];
  const float* f1  = (const float*)d_in[1];
  const float* f2  = (const float*)d_in[2];
  const float* wts = (const float*)d_in[3];
  float* out = (float*)d_out;
  char* ws = (char*)d_ws;

  unsigned short* f1b = (unsigned short*)(ws + OFF_F1B);
  unsigned short* f2b = (unsigned short*)(ws + OFF_F2B);
  float4* pp4 = (float4*)(ws + OFF_PP4);
  float* nb2 = (float*)(ws + OFF_NB2);
  float* pZf = (float*)(ws + OFF_PZF);
  float* Zp = (float*)(ws + OFF_ZP);
  float* Sp = (float*)(ws + OFF_SP);
  float* pregs = (float*)(ws + OFF_PRG);
  float* ceparts = (float*)(ws + OFF_CEP);

  prep_kernel<<<PREP_BLOCKS, 256, 0, stream>>>(pts, f1, f2, f1b, f2b, pp4, nb2,
                                               pregs, Zp, Sp);

  dim3 grid(NN / 64, BB, CC);
  stream_kernel<<<grid, 256, 0, stream>>>(f1b, f2b, pp4, nb2, pZf, Zp, Sp);

  finalize_kernel<<<FIN_BLOCKS, 256, 0, stream>>>(pZf, Zp, Sp, wts, ceparts);

  out_kernel<<<1, 256, 0, stream>>>(ceparts, pregs, out);
}

// Round 8
// 53.664 us; speedup vs baseline: 1.7952x; 1.7952x over previous
//
#include <hip/hip_runtime.h>
#include <hip/hip_bf16.h>

#define BB 4
#define NN 4096
#define DD 64
#define TJ 64
#define CC 8                 // column chunks (grid.z)
#define CHUNK (NN / CC)      // 512 cols per block
#define NTC (CHUNK / TJ)     // 8 tiles per block
#define HPB 512              // hit capacity per block (expect ~42)
#define PREP_BLOCKS 512      // BN/32
#define FIN_BLOCKS 64        // BN/256
#define PSCALE 240.2244818f  // 200 * sqrt(log2(e)) : |p'i-p'j|^2 = PD*log2(e)
#define K2L 2.885390082f     // 2*log2(e)  (folded into f1 bf16)
#define NL2E -1.442695041f   // -log2(e)
#define LN2 0.6931471805599453f

typedef __attribute__((ext_vector_type(8))) short bf16x8;
typedef __attribute__((ext_vector_type(4))) float f32x4;

// workspace layout (bytes)
static constexpr size_t BN = (size_t)BB * NN;
static constexpr size_t OFF_F1B = 0;                          // bf16 [BN][D] (pre-scaled by K2L)
static constexpr size_t OFF_F2B = OFF_F1B + BN * DD * 2;      // bf16 [BN][D]
static constexpr size_t OFF_PP4 = OFF_F2B + BN * DD * 2;      // float4 [BN] {p'x,p'y,p'z,|p'|^2}
static constexpr size_t OFF_NB2 = OFF_PP4 + BN * 16;          // f32 [BN]  -|f2|^2*log2e
static constexpr size_t OFF_PZF = OFF_NB2 + BN * 4;           // f32 [CC][BN] partial Zf
static constexpr size_t OFF_ZP  = OFF_PZF + (size_t)CC * BN * 4;  // f32 [BN] (zeroed by prep)
static constexpr size_t OFF_SP  = OFF_ZP + BN * 4;            // f32 [BN] (zeroed by prep)
static constexpr size_t OFF_PRG = OFF_SP + BN * 4;            // f32 [PREP_BLOCKS] reg partials
static constexpr size_t OFF_CEP = OFF_PRG + PREP_BLOCKS * 4;  // f32 [FIN_BLOCKS] ce partials

__device__ __forceinline__ unsigned short f2bf(float x) {
  unsigned int u = __float_as_uint(x);
  u += 0x7FFFu + ((u >> 16) & 1u);   // round-to-nearest-even
  return (unsigned short)(u >> 16);
}
__device__ __forceinline__ float bf2f(short s) {
  return __uint_as_float(((unsigned)(unsigned short)s) << 16);
}
__device__ __forceinline__ void gl_lds16(const void* g, void* lds) {
  __builtin_amdgcn_global_load_lds((const __attribute__((address_space(1))) unsigned int*)g,
                                   (__attribute__((address_space(3))) unsigned int*)lds, 16, 0, 0);
}

// ---- prep: bf16 convert (f1 scaled) + norms + points + reg partial + Zp/Sp zero ----
__global__ __launch_bounds__(256) void prep_kernel(
    const float* __restrict__ pts, const float* __restrict__ f1,
    const float* __restrict__ f2, unsigned short* __restrict__ f1b,
    unsigned short* __restrict__ f2b, float4* __restrict__ pp4,
    float* __restrict__ nb2, float* __restrict__ pregs,
    float* __restrict__ Zp, float* __restrict__ Sp) {
  const int R0 = blockIdx.x * 32;
  const int t = threadIdx.x;
  const float4* f1v = (const float4*)(f1 + (size_t)R0 * DD);
  const float4* f2v = (const float4*)(f2 + (size_t)R0 * DD);
  ushort4* o1 = (ushort4*)(f1b + (size_t)R0 * DD);
  ushort4* o2 = (ushort4*)(f2b + (size_t)R0 * DD);
  if (t < 32) { Zp[R0 + t] = 0.f; Sp[R0 + t] = 0.f; }
  float regsum = 0.f;
#pragma unroll
  for (int p = 0; p < 2; ++p) {
    int c = t + p * 256;                 // float4-chunk in [0,512); row = R0 + c/16
    float4 a = f1v[c], bv = f2v[c];
    ushort4 ua, ub;
    ua.x = f2bf(a.x * K2L); ua.y = f2bf(a.y * K2L);
    ua.z = f2bf(a.z * K2L); ua.w = f2bf(a.w * K2L);
    ub.x = f2bf(bv.x); ub.y = f2bf(bv.y); ub.z = f2bf(bv.z); ub.w = f2bf(bv.w);
    o1[c] = ua; o2[c] = ub;
    float s1 = a.x * a.x + a.y * a.y + a.z * a.z + a.w * a.w;
    float s2 = bv.x * bv.x + bv.y * bv.y + bv.z * bv.z + bv.w * bv.w;
    regsum += s1 + s2;
    float s2r = s2;
#pragma unroll
    for (int m = 1; m <= 8; m <<= 1) s2r += __shfl_xor(s2r, m, 64);
    if ((t & 15) == 0) nb2[R0 + (c >> 4)] = NL2E * s2r;
  }
  if (t < 32) {
    int row = R0 + t;
    float px = pts[row * 3 + 0] * PSCALE;
    float py = pts[row * 3 + 1] * PSCALE;
    float pz = pts[row * 3 + 2] * PSCALE;
    pp4[row] = make_float4(px, py, pz, fmaf(px, px, fmaf(py, py, pz * pz)));
  }
  __shared__ float red[256];
  red[t] = regsum;
  __syncthreads();
  for (int k = 128; k > 0; k >>= 1) {
    if (t < k) red[t] += red[t + k];
    __syncthreads();
  }
  if (t == 0) pregs[blockIdx.x] = red[0];
}

// ---- dense: Zf (MFMA+exp2) + point hit-scan, 4-buffer counted-vmcnt pipeline ----
// grid (NN/128, BB, CC), block 256. Wave owns 32 rows x 512 cols; block 128 rows.
__global__ __launch_bounds__(256, 4) void dense_kernel(
    const unsigned short* __restrict__ f1b, const unsigned short* __restrict__ f2b,
    const float4* __restrict__ pp4, const float* __restrict__ nb2g,
    float* __restrict__ pZf, float* __restrict__ Zp, float* __restrict__ Sp) {
  __shared__ unsigned short f2t[4][TJ * DD];   // 32KB, 4 bufs, XOR-swizzled 16B chunks
  __shared__ uint2 hbuf[HPB];                  // 4KB hit buffer
  __shared__ unsigned hcnt;

  const int b = blockIdx.y;
  const int ck = blockIdx.z;
  const int rowbase = blockIdx.x * 128;
  const int tid = threadIdx.x;
  const int wave = tid >> 6;
  const int lane = tid & 63;
  const int l15 = lane & 15;
  const int l4 = lane >> 4;
  if (tid == 0) hcnt = 0;

  // A fragments: 2 row-subtiles of 16 (wave rows = rowbase + wave*32 .. +32)
  const int wrow = rowbase + wave * 32;
  bf16x8 af[2][2];
#pragma unroll
  for (int rt = 0; rt < 2; ++rt) {
    const unsigned short* fr = f1b + ((size_t)(b * NN + wrow + rt * 16 + l15)) * DD;
    af[rt][0] = *(const bf16x8*)(fr + l4 * 8);
    af[rt][1] = *(const bf16x8*)(fr + 32 + l4 * 8);
  }
  // point-scan row constants: 4 rows per thread (rows fixed for whole block)
  float m2x[4], m2y[4], m2z[4], xw[4];
#pragma unroll
  for (int k = 0; k < 4; ++k) {
    float4 p = pp4[b * NN + rowbase + (tid & 31) * 4 + k];
    m2x[k] = -2.f * p.x; m2y[k] = -2.f * p.y; m2z[k] = -2.f * p.z; xw[k] = p.w;
  }

  float Zf[2][4];
#pragma unroll
  for (int rt = 0; rt < 2; ++rt)
#pragma unroll
    for (int r = 0; r < 4; ++r) Zf[rt][r] = 0.f;

  auto stage = [&](int buf, int col0) {   // 2 global_load_lds per thread
    const char* gbase = (const char*)(f2b + ((size_t)(b * NN + col0)) * DD);
    {
      int r = tid >> 3, s = tid & 7;
      gl_lds16(gbase + r * 128 + (s ^ (r & 7)) * 16, (char*)&f2t[buf][0] + wave * 1024);
    }
    {
      int c = tid + 256, r = c >> 3, s = c & 7;
      gl_lds16(gbase + r * 128 + (s ^ (r & 7)) * 16, (char*)&f2t[buf][0] + wave * 1024 + 4096);
    }
  };

  const int colbase = ck * CHUNK;
  // prologue: 3 tiles in flight
  stage(0, colbase);
  stage(1, colbase + TJ);
  stage(2, colbase + 2 * TJ);

  const int swz0 = ((l4 ^ (l15 & 7)) << 4);
  const int swz1 = (((4 + l4) ^ (l15 & 7)) << 4);
  const float4* pcol = pp4 + b * NN + colbase;      // batch-local col points
  const float* nbcol = nb2g + b * NN + colbase;

  for (int jt = 0; jt < NTC; ++jt) {
    // counted wait: tile jt's DMA done (in-order vmcnt retirement)
    __builtin_amdgcn_sched_barrier(0);
    if (jt + 2 < NTC)       asm volatile("s_waitcnt vmcnt(4)" ::: "memory");
    else if (jt + 2 == NTC) asm volatile("s_waitcnt vmcnt(2)" ::: "memory");
    else                    asm volatile("s_waitcnt vmcnt(0)" ::: "memory");
    __builtin_amdgcn_sched_barrier(0);
    __builtin_amdgcn_s_barrier();
    __builtin_amdgcn_sched_barrier(0);
    if (jt + 3 < NTC) stage((jt + 3) & 3, colbase + (jt + 3) * TJ);
    __builtin_amdgcn_sched_barrier(0);

    const int cur = jt & 3;
    const char* f2c = (const char*)f2t + cur * 8192 + l15 * 128;
    // --- fea: 4 sub-tiles of 16 cols ---
#pragma unroll
    for (int s16 = 0; s16 < 4; ++s16) {
      bf16x8 bf0 = *(const bf16x8*)(f2c + swz0 + s16 * 2048);
      bf16x8 bf1 = *(const bf16x8*)(f2c + swz1 + s16 * 2048);
      float nb = nbcol[jt * 64 + s16 * 16 + l15];   // L1/L2 global, off the LDS pipe
      f32x4 a0 = {nb, nb, nb, nb}, a1 = a0;
      a0 = __builtin_amdgcn_mfma_f32_16x16x32_bf16(af[0][0], bf0, a0, 0, 0, 0);
      a0 = __builtin_amdgcn_mfma_f32_16x16x32_bf16(af[0][1], bf1, a0, 0, 0, 0);
      a1 = __builtin_amdgcn_mfma_f32_16x16x32_bf16(af[1][0], bf0, a1, 0, 0, 0);
      a1 = __builtin_amdgcn_mfma_f32_16x16x32_bf16(af[1][1], bf1, a1, 0, 0, 0);
#pragma unroll
      for (int r = 0; r < 4; ++r) {
        Zf[0][r] += __builtin_amdgcn_exp2f(a0[r]);
        Zf[1][r] += __builtin_amdgcn_exp2f(a1[r]);
      }
    }
    // --- point scan: this thread: 4 rows x 8 cols of the 128x64 tile ---
#pragma unroll
    for (int g = 0; g < 2; ++g) {
      int c0 = jt * 64 + (tid >> 5) * 8 + g * 4;    // CHUNK-local col
      float4 pj0 = pcol[c0], pj1 = pcol[c0 + 1], pj2 = pcol[c0 + 2], pj3 = pcol[c0 + 3];
      float pd[4][4];
#pragma unroll
      for (int k = 0; k < 4; ++k) {
        pd[0][k] = fmaf(m2x[k], pj0.x, fmaf(m2y[k], pj0.y, fmaf(m2z[k], pj0.z, xw[k] + pj0.w)));
        pd[1][k] = fmaf(m2x[k], pj1.x, fmaf(m2y[k], pj1.y, fmaf(m2z[k], pj1.z, xw[k] + pj1.w)));
        pd[2][k] = fmaf(m2x[k], pj2.x, fmaf(m2y[k], pj2.y, fmaf(m2z[k], pj2.z, xw[k] + pj2.w)));
        pd[3][k] = fmaf(m2x[k], pj3.x, fmaf(m2y[k], pj3.y, fmaf(m2z[k], pj3.z, xw[k] + pj3.w)));
      }
      float mn = 999.f;
#pragma unroll
      for (int c = 0; c < 4; ++c)
#pragma unroll
        for (int k = 0; k < 4; ++k) mn = fminf(mn, pd[c][k]);
      if (mn < 126.f) {
#pragma unroll
        for (int c = 0; c < 4; ++c)
#pragma unroll
          for (int k = 0; k < 4; ++k)
            if (pd[c][k] < 126.f) {
              unsigned slot = atomicAdd(&hcnt, 1u);
              if (slot < HPB)
                hbuf[slot] = make_uint2(
                    (((unsigned)((tid & 31) * 4 + k)) << 9) | (unsigned)(c0 + c),
                    __float_as_uint(pd[c][k]));
            }
      }
    }
  }

  // merge Zf across the 16 lanes sharing rows; write partials
#pragma unroll
  for (int m = 1; m <= 8; m <<= 1)
#pragma unroll
    for (int rt = 0; rt < 2; ++rt)
#pragma unroll
      for (int r = 0; r < 4; ++r) Zf[rt][r] += __shfl_xor(Zf[rt][r], m, 64);
  if (l15 == 0) {
    size_t base = (size_t)ck * BN + b * NN + wrow + l4 * 4;
#pragma unroll
    for (int rt = 0; rt < 2; ++rt)
#pragma unroll
      for (int r = 0; r < 4; ++r) pZf[base + rt * 16 + r] = Zf[rt][r];
  }

  // resolve hits: recompute bf16 dot, accumulate global Zp/Sp
  __syncthreads();
  unsigned n = hcnt; if (n > HPB) n = HPB;
  for (unsigned idx = tid; idx < n; idx += 256) {
    uint2 h = hbuf[idx];
    unsigned rowg = b * NN + rowbase + (h.x >> 9);
    unsigned jg = b * NN + colbase + (h.x & 511u);
    const bf16x8* A = (const bf16x8*)(f1b + (size_t)rowg * DD);
    const bf16x8* Bv = (const bf16x8*)(f2b + (size_t)jg * DD);
    float dot = 0.f;                       // = K2L * dot(f1,f2)  (f1 pre-scaled)
#pragma unroll
    for (int c = 0; c < 8; ++c) {
      bf16x8 av = A[c], bv = Bv[c];
#pragma unroll
      for (int e = 0; e < 8; ++e) dot = fmaf(bf2f(av[e]), bf2f(bv[e]), dot);
    }
    float t2 = dot + nb2g[jg];             // (2dot - b2)*log2e
    float g = __builtin_amdgcn_exp2f(-__uint_as_float(h.y));
    atomicAdd(&Zp[rowg], g);
    atomicAdd(&Sp[rowg], g * t2);
  }
}

// ---------------- finalize: ce per row, partial per block ---------------------
__global__ __launch_bounds__(256) void finalize_kernel(
    const float* __restrict__ pZf, const float* __restrict__ Zp,
    const float* __restrict__ Sp, const float* __restrict__ wts,
    float* __restrict__ ceparts) {
  const int i = blockIdx.x * 256 + threadIdx.x;    // row in [0, BN)
  float zf = 0.f;
#pragma unroll
  for (int c = 0; c < CC; ++c) zf += pZf[(size_t)c * BN + i];
  float ce = wts[i] * (LN2 * (__builtin_amdgcn_logf(zf) - Sp[i] / Zp[i]));
  __shared__ float red[256];
  red[threadIdx.x] = ce;
  __syncthreads();
  for (int k = 128; k > 0; k >>= 1) {
    if (threadIdx.x < k) red[threadIdx.x] += red[threadIdx.x + k];
    __syncthreads();
  }
  if (threadIdx.x == 0) ceparts[blockIdx.x] = red[0];
}

// ---------------- out: reduce partials into d_out (plain stores) --------------
__global__ __launch_bounds__(256) void out_kernel(
    const float* __restrict__ ceparts, const float* __restrict__ pregs,
    float* __restrict__ out) {
  const int w = threadIdx.x >> 6, lane = threadIdx.x & 63;
  float ps = pregs[w * 128 + lane] + pregs[w * 128 + 64 + lane];
#pragma unroll
  for (int m = 1; m <= 32; m <<= 1) ps += __shfl_xor(ps, m, 64);
  float cs = (lane < 16) ? ceparts[w * 16 + lane] : 0.f;
#pragma unroll
  for (int m = 1; m <= 8; m <<= 1) cs += __shfl_xor(cs, m, 64);
  if (lane == 0) {
    out[w] = cs;
    out[BB + w] = ps * (1.f / ((float)NN * DD));
  }
}

extern "C" void kernel_launch(void* const* d_in, const int* in_sizes, int n_in,
                              void* d_out, int out_size, void* d_ws, size_t ws_size,
                              hipStream_t stream) {
  const float* pts = (const float*)d_in[0];
  const float* f1  = (const float*)d_in[1];
  const float* f2  = (const float*)d_in[2];
  const float* wts = (const float*)d_in[3];
  float* out = (float*)d_out;
  char* ws = (char*)d_ws;

  unsigned short* f1b = (unsigned short*)(ws + OFF_F1B);
  unsigned short* f2b = (unsigned short*)(ws + OFF_F2B);
  float4* pp4 = (float4*)(ws + OFF_PP4);
  float* nb2 = (float*)(ws + OFF_NB2);
  float* pZf = (float*)(ws + OFF_PZF);
  float* Zp = (float*)(ws + OFF_ZP);
  float* Sp = (float*)(ws + OFF_SP);
  float* pregs = (float*)(ws + OFF_PRG);
  float* ceparts = (float*)(ws + OFF_CEP);

  prep_kernel<<<PREP_BLOCKS, 256, 0, stream>>>(pts, f1, f2, f1b, f2b, pp4, nb2,
                                               pregs, Zp, Sp);

  dim3 grid(NN / 128, BB, CC);
  dense_kernel<<<grid, 256, 0, stream>>>(f1b, f2b, pp4, nb2, pZf, Zp, Sp);

  finalize_kernel<<<FIN_BLOCKS, 256, 0, stream>>>(pZf, Zp, Sp, wts, ceparts);

  out_kernel<<<1, 256, 0, stream>>>(ceparts, pregs, out);
}